// Round 7
// baseline (107.019 us; speedup 1.0000x reference)
//
#include <hip/hip_runtime.h>

#define BB 4
#define CC 32
#define HH 512
#define WW 512
#define TS 16
#define SH 13          // staged rows per wave: wave_row_base-4 .. +8
#define SW 25          // staged cols: tile_col_base-4 .. +20 (25 coprime to 32 -> bank rotation)
#define CALLOC 384     // 6 * 64 staged slots (325 real + pad)

typedef float f2v __attribute__((ext_vector_type(2), aligned(4)));
typedef const __attribute__((address_space(1))) float gfloat;
typedef __attribute__((address_space(3))) float lfloat;

__device__ __forceinline__ void stage4(const float* g, float* l) {
    // async global->LDS, 4B/lane; dest = uniform base + lane*4 (linear)
    __builtin_amdgcn_global_load_lds((gfloat*)g, (lfloat*)l, 4, 0, 0);
}

__global__ __launch_bounds__(256, 6) void warp_bilinear_kernel(
    const float* __restrict__ src,
    const float* __restrict__ flow,
    float* __restrict__ out)
{
    const int HW = HH * WW;
    // 4 waves x 2 buffers x 384 floats = 12 KB -> LDS never the occupancy limit
    __shared__ float smem[4 * 2 * CALLOC];

    // Bijective XCD swizzle (gridDim.x == 4096, divisible by 8).
    int nper = gridDim.x >> 3;
    int bid = (blockIdx.x & 7) * nper + (blockIdx.x >> 3);

    int b  = bid >> 10;
    int ty = (bid >> 5) & 31;
    int tx = bid & 31;

    int tid  = threadIdx.x;
    int lane = tid & 63;
    int wv   = tid >> 6;

    // wave owns a 16x4 pixel patch; lane = (ly in 0..3, lx in 0..15)
    int lx = lane & 15;
    int ly = lane >> 4;
    int wrow = ty * TS + (wv << 2);
    int h = wrow + ly;
    int w = tx * TS + lx;
    int p = h * WW + w;

    int row_base = wrow - 4;          // staged window origin (may be <0, clamped at source)
    int col_base = tx * TS - 4;

    const float* sb = src + (size_t)b * CC * HW;
    float*       ob = out + (size_t)b * CC * HW;

    float fy = __builtin_nontemporal_load(flow + (b * 2 + 0) * HW + p);
    float fx = __builtin_nontemporal_load(flow + (b * 2 + 1) * HW + p);

    float yy = fminf(fmaxf((float)h + fy, 0.0f), (float)(HH - 1));
    float xx = fminf(fmaxf((float)w + fx, 0.0f), (float)(WW - 1));

    // Border fold (== reference exactly): x1 = x0+1 always; weight 0/1 at border.
    int y0 = min((int)floorf(yy), HH - 2);
    int x0 = min((int)floorf(xx), WW - 2);
    float wy = yy - (float)y0;
    float wx = xx - (float)x0;

    float w00 = (1.0f - wy) * (1.0f - wx);
    float w01 = (1.0f - wy) * wx;
    float w10 = wy * (1.0f - wx);
    float w11 = wy * wx;

    int r0 = y0 - row_base;
    int c0 = x0 - col_base;
    bool in_tile = ((unsigned)r0 <= (SH - 2)) && ((unsigned)c0 <= (SW - 2));
    int rc = min(max(r0, 0), SH - 2);     // clamp so LDS reads stay in-bounds
    int cce = min(max(c0, 0), SW - 2);
    int lbase = rc * SW + cce;            // taps: +0, +1, +SW, +SW+1 (ds_read2 pairs)

    int i0 = y0 * WW + x0;                // rare out-of-halo fallback (|flow| > ~4)
    int i1 = i0 + WW;

    // Per-lane staging source offsets (channel-invariant). Slot e -> (r = e/25,
    // c = e%25); clamped source coords make border tiles AND pad slots (e>=325)
    // valid; staged slot (r,c) == src[row_base+r][col_base+c] whenever that
    // coord is in-image, which covers every tap any in_tile pixel can request.
    int soff[6];
    #pragma unroll
    for (int it = 0; it < 6; ++it) {
        int e = lane + (it << 6);
        int r = e / SW;
        r = min(r, SH - 1);
        int c = e - r * SW;
        int srow = min(max(row_base + r, 0), HH - 1);
        int scol = min(max(col_base + c, 0), WW - 1);
        soff[it] = srow * WW + scol;
    }

    float* lwb = smem + wv * (2 * CALLOC);   // wave-private slab -> NO barriers

    // prologue: stage channel 0 into buffer 0
    const float* cs = sb;
    #pragma unroll
    for (int it = 0; it < 6; ++it)
        stage4(cs + soff[it], lwb + (it << 6));

    float* op = ob + p;

    #pragma unroll
    for (int ch = 0; ch < CC; ++ch) {
        const float* lb = lwb + (ch & 1) * CALLOC;
        if (ch + 1 < CC) {
            const float* ns = cs + HW;
            float* nb = lwb + ((ch + 1) & 1) * CALLOC;
            #pragma unroll
            for (int it = 0; it < 6; ++it)
                stage4(ns + soff[it], nb + (it << 6));
            // In-order VMEM retirement: allowing the newest 7 ops (1 nt store
            // from last iter + 6 next-channel loads) to remain in flight
            // guarantees THIS channel's 6 staging loads have completed,
            // without draining the pipeline (T4: never vmcnt(0) in the loop).
            asm volatile("s_waitcnt vmcnt(7)" ::: "memory");
        } else {
            asm volatile("s_waitcnt vmcnt(1)" ::: "memory");  // allow last store only
        }
        float v = lb[lbase]      * w00 + lb[lbase + 1]      * w01
                + lb[lbase + SW] * w10 + lb[lbase + SW + 1] * w11;
        if (!in_tile) {   // execz-skipped for ~99.4% of waves
            f2v t  = *(const f2v*)(cs + i0);
            f2v bt = *(const f2v*)(cs + i1);
            v = t.x * w00 + t.y * w01 + bt.x * w10 + bt.y * w11;
        }
        __builtin_nontemporal_store(v, op);
        cs += HW;
        op += HW;
    }
}

extern "C" void kernel_launch(void* const* d_in, const int* in_sizes, int n_in,
                              void* d_out, int out_size, void* d_ws, size_t ws_size,
                              hipStream_t stream) {
    const float* src  = (const float*)d_in[0];
    const float* flow = (const float*)d_in[1];
    float* out = (float*)d_out;

    const int nblocks = BB * (HH / TS) * (WW / TS);   // 4096, divisible by 8
    warp_bilinear_kernel<<<nblocks, 256, 0, stream>>>(src, flow, out);
}

// Round 8
// 90.253 us; speedup vs baseline: 1.1858x; 1.1858x over previous
//
#include <hip/hip_runtime.h>

#define BB 4
#define CC 32
#define HH 512
#define WW 512
#define TS 16
#define SW 36        // padded LDS pitch: bank rotates by 4 per row; 4 | 36 -> stage16 chunks never straddle rows
#define NSLOT 1024   // 4 panels x 256 floats = 28.4 rows staged (rows 0..27 full)
#define ROWS_OK 26   // taps: r0 in [0,26] so r0+1 <= 27
#define COLS_OK 34   // c0 in [0,34] so c0+1 <= 35

typedef float f2v __attribute__((ext_vector_type(2), aligned(4)));
typedef const __attribute__((address_space(1))) float gfloat;
typedef __attribute__((address_space(3))) float lfloat;

#define WAITVM1() asm volatile("s_waitcnt vmcnt(1)" ::: "memory")
#define WAITVM2() asm volatile("s_waitcnt vmcnt(2)" ::: "memory")
#define WAITLGKM() asm volatile("s_waitcnt lgkmcnt(0)" ::: "memory")

__device__ __forceinline__ void stage16(const float* g, float* l) {
    // async global->LDS: per-lane global src (contiguous 16B each), LDS dest
    // = wave-uniform base + lane*16B (linear). TA fast path.
    __builtin_amdgcn_global_load_lds((gfloat*)g, (lfloat*)l, 16, 0, 0);
}

__global__ __launch_bounds__(256) void warp_bilinear_kernel(
    const float* __restrict__ src,
    const float* __restrict__ flow,
    float* __restrict__ out)
{
    const int HW = HH * WW;
    __shared__ float smem[2 * NSLOT];   // 8 KB -> never the occupancy limit

    // Bijective XCD swizzle (gridDim.x == 4096, divisible by 8).
    int nper = gridDim.x >> 3;
    int bid = (blockIdx.x & 7) * nper + (blockIdx.x >> 3);

    int b  = bid >> 10;
    int ty = (bid >> 5) & 31;
    int tx = bid & 31;

    int tid  = threadIdx.x;
    int lane = tid & 63;
    int wv   = tid >> 6;        // wave wv stages panel wv (floats [wv*256, wv*256+256))
    int lx   = tid & 15;
    int ly   = tid >> 4;

    int h = ty * TS + ly;
    int w = tx * TS + lx;
    int p = h * WW + w;

    int row_base = ty * TS - 4;     // staged window origin
    int col_base = tx * TS - 4;

    const float* sb = src + (size_t)b * CC * HW;
    float*       ob = out + (size_t)b * CC * HW;

    float fy = __builtin_nontemporal_load(flow + (b * 2 + 0) * HW + p);
    float fx = __builtin_nontemporal_load(flow + (b * 2 + 1) * HW + p);

    float yy = fminf(fmaxf((float)h + fy, 0.0f), (float)(HH - 1));
    float xx = fminf(fmaxf((float)w + fx, 0.0f), (float)(WW - 1));

    // Border fold (== reference exactly): x1 = x0+1 / y1 = y0+1 always,
    // with the off-edge tap getting weight exactly 0.
    int y0 = min((int)floorf(yy), HH - 2);
    int x0 = min((int)floorf(xx), WW - 2);
    float wy = yy - (float)y0;
    float wx = xx - (float)x0;

    float w00 = (1.0f - wy) * (1.0f - wx);
    float w01 = (1.0f - wy) * wx;
    float w10 = wy * (1.0f - wx);
    float w11 = wy * wx;

    int r0 = y0 - row_base;
    int c0 = x0 - col_base;
    // Staged slot (r,c) holds src[clamp(row_base+r)][clamp(col_base+c)], which
    // equals the true tap whenever the tap coord is in-image -> any r0<=26,
    // c0<=34 is served exactly (image-edge clamps match reference semantics).
    bool in_tile = ((unsigned)r0 <= ROWS_OK) && ((unsigned)c0 <= COLS_OK);
    int rc  = min(max(r0, 0), ROWS_OK);
    int cc2 = min(max(c0, 0), COLS_OK);
    int lbase = rc * SW + cc2;       // taps: +0, +1, +SW, +SW+1 (ds_read2 pairs)

    int i0 = y0 * WW + x0;           // rare out-of-halo fallback (P ~ 6e-5/pixel)
    int i1 = i0 + WW;

    bool interior_x = (tx >= 1) && (tx <= 30);   // block-uniform

    // Interior staging source for this lane: float slot f = wv*256 + lane*4,
    // r = f/36, c = f%36 (c in {0,4,...,32} -> chunk c..c+3 never leaves row r).
    int f  = (wv << 8) + (lane << 2);
    int rr = f / SW;
    int ccs = f - rr * SW;
    int srow = min(max(row_base + rr, 0), HH - 1);
    int soff = srow * WW + col_base + ccs;

    auto stage = [&](int ch, float* buf) {
        if (interior_x) {
            stage16(sb + (size_t)ch * HW + soff, buf + (wv << 8));
        } else {
            // edge-x blocks (tx=0/31): per-element clamped reg staging
            const float* s = sb + (size_t)ch * HW;
            #pragma unroll
            for (int it = 0; it < 4; ++it) {
                int s2 = (wv << 8) + (it << 6) + lane;
                int r2 = s2 / SW, c2 = s2 - r2 * SW;
                int sr = min(max(row_base + r2, 0), HH - 1);
                int sc = min(max(col_base + c2, 0), WW - 1);
                buf[s2] = s[sr * WW + sc];
            }
        }
    };

    auto compute = [&](int ch, const float* lb) {
        float l00 = lb[lbase],      l01 = lb[lbase + 1];
        float l10 = lb[lbase + SW], l11 = lb[lbase + SW + 1];
        float v = l00 * w00 + l01 * w01 + l10 * w10 + l11 * w11;
        if (!in_tile) {              // execz-skipped ~99.6% of waves
            const float* s = sb + (size_t)ch * HW;
            f2v t  = *(const f2v*)(s + i0);
            f2v bt = *(const f2v*)(s + i1);
            v = t.x * w00 + t.y * w01 + bt.x * w10 + bt.y * w11;
        }
        __builtin_nontemporal_store(v, ob + (size_t)ch * HW + p);
    };

    float* buf0 = smem;
    float* buf1 = smem + NSLOT;

    // ---- peeled pipeline: both buffers primed, counted waits thereafter ----
    stage(0, buf0);
    stage(1, buf1);
    if (interior_x) WAITVM1(); else WAITLGKM();   // stage(0) complete
    __builtin_amdgcn_s_barrier();
    compute(0, buf0);
    __builtin_amdgcn_s_barrier();                 // reads of buf0 done block-wide

    for (int ch = 1; ch <= 30; ++ch) {
        float* nb = ((ch + 1) & 1) ? buf1 : buf0;   // buffer of ch-1, safe now
        stage(ch + 1, nb);
        // per-wave VMEM queue (oldest first): stage(ch), store(ch-1), stage(ch+1)
        // -> vmcnt(2) guarantees stage(ch) landed without draining the store.
        if (interior_x) WAITVM2(); else WAITLGKM();
        __builtin_amdgcn_s_barrier();
        compute(ch, (ch & 1) ? buf1 : buf0);
        __builtin_amdgcn_s_barrier();
    }

    // ch = 31: queue = stage(31), store(30) -> vmcnt(1)
    if (interior_x) WAITVM1(); else WAITLGKM();
    __builtin_amdgcn_s_barrier();
    compute(31, buf1);
}

extern "C" void kernel_launch(void* const* d_in, const int* in_sizes, int n_in,
                              void* d_out, int out_size, void* d_ws, size_t ws_size,
                              hipStream_t stream) {
    const float* src  = (const float*)d_in[0];
    const float* flow = (const float*)d_in[1];
    float* out = (float*)d_out;

    const int nblocks = BB * (HH / TS) * (WW / TS);   // 4096, divisible by 8
    warp_bilinear_kernel<<<nblocks, 256, 0, stream>>>(src, flow, out);
}